// Round 19
// baseline (214.539 us; speedup 1.0000x reference)
//
#include <hip/hip_runtime.h>
#include <hip/hip_bf16.h>
#include <math.h>

// Problem constants: B=4, T=2048, C=1024, H=16, D=64
#define B_  4
#define T_  2048
#define C_  1024
#define NH  16
#define HD  64
#define M_  (B_ * T_)        // 8192 rows
#define N_QKV (3 * C_)       // 3072
#define KDIM 1024
#define SCALE2 0.18033688011112042f   // (1/sqrt(64)) * log2(e), prefolded into Q

typedef __attribute__((ext_vector_type(8))) short short8;
typedef __attribute__((ext_vector_type(4))) short bs4;
typedef __attribute__((ext_vector_type(4))) float f32x4;
typedef __attribute__((ext_vector_type(16))) float f32x16;
typedef __attribute__((ext_vector_type(4))) unsigned u32x4;

__device__ __forceinline__ short f2bs(float f) {
  __hip_bfloat16 h = __float2bfloat16(f);
  return *reinterpret_cast<short*>(&h);
}
// packed f32x2 -> bf16x2 (RNE), compiler-lowered (v_cvt_pk_bf16_f32 on gfx950)
__device__ __forceinline__ unsigned packrn(float a, float b) {
  __hip_bfloat162 h = __float22bfloat162_rn(float2{a, b});
  unsigned u;
  __builtin_memcpy(&u, &h, 4);
  return u;
}

__device__ __forceinline__ void gload16(const void* g, void* l) {
  __builtin_amdgcn_global_load_lds(
      (const __attribute__((address_space(1))) void*)g,
      (__attribute__((address_space(3))) void*)l, 16, 0, 0);
}

// ---------------------------------------------------------------------------
// Fused prep (round-16, verbatim): xcast + W_attn^T + W_proj^T
// ---------------------------------------------------------------------------
__device__ __forceinline__ void wtrans_body(
    const float* __restrict__ W, short* __restrict__ Wt, int Ncols, int qcols,
    int bid2, int tid, short (*t)[33])
{
  const int nb = Ncols / 32;
  const int bn = bid2 % nb, bk = bid2 / nb;
  const int r = tid >> 3, c4 = (tid & 7) * 4;
  const float cs = (bn * 32 < qcols) ? SCALE2 : 1.f;
  f32x4 v = *reinterpret_cast<const f32x4*>(
      W + (size_t)(bk * 32 + r) * Ncols + bn * 32 + c4);
  #pragma unroll
  for (int j = 0; j < 4; ++j) t[r][c4 + j] = f2bs(v[j] * cs);
  __syncthreads();
  bs4 o;
  #pragma unroll
  for (int j = 0; j < 4; ++j) o[j] = t[c4 + j][r];
  *reinterpret_cast<bs4*>(Wt + (size_t)(bn * 32 + r) * KDIM + bk * 32 + c4) = o;
}

__global__ __launch_bounds__(256) void prep_kernel(
    const float* __restrict__ x,  short* __restrict__ xb,
    const float* __restrict__ Wa, short* __restrict__ WaT,
    const float* __restrict__ Wp, short* __restrict__ WpT)
{
  __shared__ short t[32][33];
  const int bid = blockIdx.x;
  const int tid = threadIdx.x;
  if (bid < 4096) {
    const int i = (bid * 256 + tid) * 8;
    f32x4 a = *reinterpret_cast<const f32x4*>(x + i);
    f32x4 b = *reinterpret_cast<const f32x4*>(x + i + 4);
    short8 o;
    #pragma unroll
    for (int j = 0; j < 4; ++j) { o[j] = f2bs(a[j]); o[4 + j] = f2bs(b[j]); }
    *reinterpret_cast<short8*>(xb + i) = o;
  } else if (bid < 7168) {
    wtrans_body(Wa, WaT, N_QKV, C_, bid - 4096, tid, t);
  } else {
    wtrans_body(Wp, WpT, C_, 0, bid - 7168, tid, t);
  }
}

// ---------------------------------------------------------------------------
// GEMM v2 (BK=64) — round-15/16 kernel verbatim.
// ---------------------------------------------------------------------------
template<bool OUT_BF16>
__global__ __launch_bounds__(256) void gemm128b_kernel(
    const short* __restrict__ A, const short* __restrict__ Bt,
    const float* __restrict__ bias, void* __restrict__ outptr, int N, int nq)
{
  __shared__ short As[128 * 64];
  __shared__ short Bs[128 * 64];

  const int tid  = threadIdx.x;
  const int lane = tid & 63;
  const int w    = tid >> 6;
  const int wr   = w >> 1, wc = w & 1;
  const int rl   = lane & 15, kg = lane >> 4;
  const int nblk = N >> 7;
  const int m0 = (blockIdx.x / nblk) << 7;
  const int n0 = (blockIdx.x % nblk) << 7;

  f32x4 acc[4][4] = {};

  const int srow = w * 8 + (lane >> 3);
  const int scol = ((lane & 7) ^ ((lane >> 3) & 7)) * 8;
  const short* pa = A  + (size_t)(m0 + srow) * KDIM + scol;
  const short* pb = Bt + (size_t)(n0 + srow) * KDIM + scol;

  for (int k0 = 0; k0 < KDIM; k0 += 64) {
    __syncthreads();
    #pragma unroll
    for (int i = 0; i < 4; ++i) {
      gload16(pa + (size_t)i * 32 * KDIM + k0, &As[i * 2048 + w * 512]);
      gload16(pb + (size_t)i * 32 * KDIM + k0, &Bs[i * 2048 + w * 512]);
    }
    __syncthreads();

    #pragma unroll
    for (int kk = 0; kk < 2; ++kk) {
      const int sl = ((kk * 4 + kg) ^ (rl & 7)) * 8;
      short8 af[4], bf[4];
      #pragma unroll
      for (int i = 0; i < 4; ++i) {
        af[i] = *reinterpret_cast<short8*>(&As[(wr * 64 + i * 16 + rl) * 64 + sl]);
        bf[i] = *reinterpret_cast<short8*>(&Bs[(wc * 64 + i * 16 + rl) * 64 + sl]);
      }
      #pragma unroll
      for (int mi = 0; mi < 4; ++mi)
        #pragma unroll
        for (int ni = 0; ni < 4; ++ni)
          acc[mi][ni] = __builtin_amdgcn_mfma_f32_16x16x32_bf16(
              af[mi], bf[ni], acc[mi][ni], 0, 0, 0);
    }
  }

  #pragma unroll
  for (int ni = 0; ni < 4; ++ni) {
    const int col = n0 + wc * 64 + ni * 16 + rl;
    float bv = bias[col];
    if (col < nq) bv *= SCALE2;
    #pragma unroll
    for (int mi = 0; mi < 4; ++mi) {
      #pragma unroll
      for (int r = 0; r < 4; ++r) {
        const int row = m0 + wr * 64 + mi * 16 + kg * 4 + r;
        const float v = acc[mi][ni][r] + bv;
        if constexpr (OUT_BF16)
          ((short*)outptr)[(size_t)row * N + col] = f2bs(v);
        else
          ((float*)outptr)[(size_t)row * N + col] = v;
      }
    }
  }
}

// ---------------------------------------------------------------------------
// MFMA flash attention v14 (causal): 8-WAVE PAIRED BLOCKS.
// Block = 512 thr = 8 waves: waves 0-3 handle q-tile qiH = 15-gb (heavy),
// waves 4-7 handle qiL = gb (light); gb = bid>>6, grid 512.
// One shared K/V staging stream per block (loop nkb = heavy's 2*qiH+2;
// light waves' existing kmin-guard skips their out-of-range tiles).
// Staging: 512 threads share the 16KB/tile -> per-thread ops halved,
// and light q-tiles no longer stage their own K/V (-26% L2 traffic).
// Per-wave compute bodies verbatim from round-18 (tree reductions kept).
// ---------------------------------------------------------------------------
__global__ __launch_bounds__(512) void attn_mfma14_kernel(
    const short* __restrict__ qkv, short* __restrict__ y)
{
  __shared__ short Ks[2][64 * 64];
  __shared__ short Vt[2][64 * 64];

  const int tid  = threadIdx.x;
  const int lane = tid & 63;
  const int w4   = (tid >> 6) & 3;      // wave within q-tile group
  const int wgrp = tid >> 8;            // 0 = heavy, 1 = light
  const int q32  = lane & 31;
  const int hi   = lane >> 5;

  const int bid  = blockIdx.x;
  const int gb   = bid >> 6;            // 0..7
  const int bh   = bid & 63;
  const int b    = bh >> 4, h = bh & 15;
  const size_t bT = (size_t)b * T_;

  const int qi   = wgrp ? gb : (15 - gb);
  const int nkb  = 2 * (15 - gb) + 2;   // heavy tile count (loop bound)

  // ---- K staging: 512 threads x 1 gload16 (row = tid>>3, XOR source) ----
  const int krow = tid >> 3;
  const int klog = (tid & 7) ^ (krow & 7);
  const size_t kbase = (bT + krow) * N_QKV + C_ + h * HD + klog * 8;
  short* const kdst = &Ks[0][tid * 8];

  // ---- V staging: thread -> key pair (2kp,2kp+1), 4 d-rows [d0,d0+4) ----
  const int kp = tid & 31;
  const int d0 = (tid >> 5) * 4;        // 0,4,8,...,60
  const int ph = ((tid >> 5) & 1) * 4;  // (d0 & 7)
  const size_t vbaseA = (bT + 2 * kp) * N_QKV + 2 * C_ + h * HD + d0;
  const size_t vbaseB = vbaseA + N_QKV;
  const int vws = ((kp >> 2) << 3) + ((kp & 3) << 1);  // short offset pre-XOR

  const int ksl = q32 & 7;              // frag-read swizzle phase

  const int wq0 = qi * 128 + w4 * 32;
  const int q   = wq0 + q32;            // this lane's q-row

  // Q B-frags: col=q, k = d = kd*16 + hi*8 + j  (pre-scaled by SCALE2)
  short8 qf[4];
  #pragma unroll
  for (int kd = 0; kd < 4; ++kd)
    qf[kd] = *reinterpret_cast<const short8*>(
        qkv + (bT + q) * N_QKV + h * HD + kd * 16 + hi * 8);

  f32x16 o0 = {}, o1 = {};              // O^T, d-tiles 0/1
  float m_ = -INFINITY, l_ = 0.f;

  // prologue: stage tile 0 into buffer 0
  {
    gload16(qkv + kbase, kdst);
    bs4 va = *reinterpret_cast<const bs4*>(qkv + vbaseA);
    bs4 vb = *reinterpret_cast<const bs4*>(qkv + vbaseB);
    #pragma unroll
    for (int j = 0; j < 4; ++j) {
      unsigned pw = (unsigned)(unsigned short)va[j] |
                    ((unsigned)(unsigned short)vb[j] << 16);
      *reinterpret_cast<unsigned*>(
          &Vt[0][(d0 + j) * 64 + (vws ^ ((ph + j) << 3))]) = pw;
    }
  }
  __syncthreads();

  int cur = 0;
  for (int kb = 0; kb < nkb; ++kb) {
    const bool more = (kb + 1 < nkb);
    bs4 va, vb;
    if (more) {
      const size_t koff = (size_t)(kb + 1) * 64 * N_QKV;
      gload16(qkv + kbase + koff, kdst + (cur ^ 1) * 4096);
      va = *reinterpret_cast<const bs4*>(qkv + vbaseA + koff);
      vb = *reinterpret_cast<const bs4*>(qkv + vbaseB + koff);
    }

    const int kmin = kb * 64;
    if (kmin <= wq0 + 31) {
      const short* ksc = &Ks[cur][0];
      const short* vtc = &Vt[cur][0];

      // ---- QK^T (swapped): keys = kmin + c*32 + (e&3)+8*(e>>2)+4*hi ----
      f32x16 s0 = {}, s1 = {};
      #pragma unroll
      for (int kd = 0; kd < 4; ++kd) {
        const int sl = ((2 * kd + hi) ^ ksl) * 8;
        short8 kf0 = *reinterpret_cast<const short8*>(&ksc[q32 * 64 + sl]);
        short8 kf1 = *reinterpret_cast<const short8*>(&ksc[(32 + q32) * 64 + sl]);
        s0 = __builtin_amdgcn_mfma_f32_32x32x16_bf16(kf0, qf[kd], s0, 0, 0, 0);
        s1 = __builtin_amdgcn_mfma_f32_32x32x16_bf16(kf1, qf[kd], s1, 0, 0, 0);
      }

      // ---- causal mask (exp2-domain scores via Q pre-scale) ----
      if (kmin + 63 > wq0) {
        const int qrel = q - kmin - 4 * hi;
        #pragma unroll
        for (int e = 0; e < 16; ++e) {
          const int ko = (e & 3) + 8 * (e >> 2);
          if (ko > qrel)      s0[e] = -INFINITY;
          if (ko + 32 > qrel) s1[e] = -INFINITY;
        }
      }

      // ---- row max: pairwise tree ----
      float mv[16];
      #pragma unroll
      for (int e = 0; e < 16; ++e) mv[e] = fmaxf(s0[e], s1[e]);
      #pragma unroll
      for (int st = 8; st >= 1; st >>= 1)
        #pragma unroll
        for (int e = 0; e < st; ++e) mv[e] = fmaxf(mv[e], mv[e + st]);
      float mx = fmaxf(mv[0], __shfl_xor(mv[0], 32, 64));

      // ---- defer-max: rescale only when max grew by > 8 (exp2 domain) ----
      if (!__all(mx <= m_ + 8.f)) {
        const float mn = fmaxf(m_, mx);
        const float cr = exp2f(m_ - mn);
        m_ = mn;
        l_ *= cr;
        #pragma unroll
        for (int e = 0; e < 16; ++e) { o0[e] *= cr; o1[e] *= cr; }
      }

      // ---- exp + sum tree ----
      #pragma unroll
      for (int e = 0; e < 16; ++e) {
        s0[e] = exp2f(s0[e] - m_);
        s1[e] = exp2f(s1[e] - m_);
      }
      float sv[16];
      #pragma unroll
      for (int e = 0; e < 16; ++e) sv[e] = s0[e] + s1[e];
      #pragma unroll
      for (int st = 8; st >= 1; st >>= 1)
        #pragma unroll
        for (int e = 0; e < st; ++e) sv[e] += sv[e + st];
      l_ += sv[0] + __shfl_xor(sv[0], 32, 64);

      // ---- P^T B-frags: packrn + shfl_xor + hi-select ----
      unsigned pk[2][4][2], sw[2][4][2];
      #pragma unroll
      for (int gg = 0; gg < 4; ++gg)
        #pragma unroll
        for (int p = 0; p < 2; ++p) {
          pk[0][gg][p] = packrn(s0[4 * gg + 2 * p], s0[4 * gg + 2 * p + 1]);
          pk[1][gg][p] = packrn(s1[4 * gg + 2 * p], s1[4 * gg + 2 * p + 1]);
          sw[0][gg][p] = (unsigned)__shfl_xor((int)pk[0][gg][p], 32, 64);
          sw[1][gg][p] = (unsigned)__shfl_xor((int)pk[1][gg][p], 32, 64);
        }

      #pragma unroll
      for (int kk = 0; kk < 4; ++kk) {
        const int c = kk >> 1, a2 = 2 * (kk & 1);
        u32x4 t;
        t[0] = hi ? sw[c][a2 + 1][0] : pk[c][a2][0];
        t[1] = hi ? sw[c][a2 + 1][1] : pk[c][a2][1];
        t[2] = hi ? pk[c][a2 + 1][0] : sw[c][a2][0];
        t[3] = hi ? pk[c][a2 + 1][1] : sw[c][a2][1];
        const short8 pb = __builtin_bit_cast(short8, t);
        const int sl = ((2 * kk + hi) ^ ksl) * 8;
        short8 vf0 = *reinterpret_cast<const short8*>(&vtc[q32 * 64 + sl]);
        short8 vf1 = *reinterpret_cast<const short8*>(&vtc[(32 + q32) * 64 + sl]);
        o0 = __builtin_amdgcn_mfma_f32_32x32x16_bf16(vf0, pb, o0, 0, 0, 0);
        o1 = __builtin_amdgcn_mfma_f32_32x32x16_bf16(vf1, pb, o1, 0, 0, 0);
      }
    }

    if (more) {
      #pragma unroll
      for (int j = 0; j < 4; ++j) {
        unsigned pw = (unsigned)(unsigned short)va[j] |
                      ((unsigned)(unsigned short)vb[j] << 16);
        *reinterpret_cast<unsigned*>(
            &Vt[cur ^ 1][(d0 + j) * 64 + (vws ^ ((ph + j) << 3))]) = pw;
      }
    }
    __syncthreads();
    cur ^= 1;
  }

  // ---- epilogue: O^T row d = dt*32 + 8g + 4hi + t, col q; bs4 stores ----
  const float inv = 1.f / l_;
  short* const yp = y + (bT + q) * C_ + h * HD;
  #pragma unroll
  for (int gg = 0; gg < 4; ++gg) {
    bs4 ov0, ov1;
    #pragma unroll
    for (int t = 0; t < 4; ++t) {
      ov0[t] = f2bs(o0[4 * gg + t] * inv);
      ov1[t] = f2bs(o1[4 * gg + t] * inv);
    }
    *reinterpret_cast<bs4*>(yp + 8 * gg + 4 * hi)      = ov0;
    *reinterpret_cast<bs4*>(yp + 32 + 8 * gg + 4 * hi) = ov1;
  }
}

extern "C" void kernel_launch(void* const* d_in, const int* in_sizes, int n_in,
                              void* d_out, int out_size, void* d_ws, size_t ws_size,
                              hipStream_t stream) {
  const float* x  = (const float*)d_in[0];
  const float* Wa = (const float*)d_in[1];
  const float* ba = (const float*)d_in[2];
  const float* Wp = (const float*)d_in[3];
  const float* bp = (const float*)d_in[4];

  short* qkvb = (short*)d_ws;                       // [8192,3072] bf16 (50.3MB)
  short* xb   = qkvb + (size_t)M_ * N_QKV;          // [8192,1024] bf16 (16.8MB)
  short* yb   = xb;                                 // overlaid: xb dead after gemm1
  short* WaT  = xb + (size_t)M_ * C_;               // [3072,1024] bf16 (6.3MB)
  short* WpT  = WaT + (size_t)N_QKV * KDIM;         // [1024,1024] bf16 (2.1MB)

  prep_kernel<<<8192, 256, 0, stream>>>(x, xb, Wa, WaT, Wp, WpT);
  gemm128b_kernel<true><<<(M_ / 128) * (N_QKV / 128), 256, 0, stream>>>(
      xb, WaT, ba, qkvb, N_QKV, C_);
  attn_mfma14_kernel<<<512, 512, 0, stream>>>(qkvb, yb);
  gemm128b_kernel<false><<<(M_ / 128) * (C_ / 128), 256, 0, stream>>>(
      yb, WpT, bp, d_out, C_, 0);
}

// Round 20
// 194.246 us; speedup vs baseline: 1.1045x; 1.1045x over previous
//
#include <hip/hip_runtime.h>
#include <hip/hip_bf16.h>
#include <math.h>

// Problem constants: B=4, T=2048, C=1024, H=16, D=64
#define B_  4
#define T_  2048
#define C_  1024
#define NH  16
#define HD  64
#define M_  (B_ * T_)        // 8192 rows
#define N_QKV (3 * C_)       // 3072
#define KDIM 1024
#define SCALE2 0.18033688011112042f   // (1/sqrt(64)) * log2(e), prefolded into Q

typedef __attribute__((ext_vector_type(8))) short short8;
typedef __attribute__((ext_vector_type(4))) short bs4;
typedef __attribute__((ext_vector_type(4))) float f32x4;
typedef __attribute__((ext_vector_type(16))) float f32x16;
typedef __attribute__((ext_vector_type(4))) unsigned u32x4;

__device__ __forceinline__ short f2bs(float f) {
  __hip_bfloat16 h = __float2bfloat16(f);
  return *reinterpret_cast<short*>(&h);
}
// packed f32x2 -> bf16x2 (RNE), compiler-lowered (v_cvt_pk_bf16_f32 on gfx950)
__device__ __forceinline__ unsigned packrn(float a, float b) {
  __hip_bfloat162 h = __float22bfloat162_rn(float2{a, b});
  unsigned u;
  __builtin_memcpy(&u, &h, 4);
  return u;
}

__device__ __forceinline__ void gload16(const void* g, void* l) {
  __builtin_amdgcn_global_load_lds(
      (const __attribute__((address_space(1))) void*)g,
      (__attribute__((address_space(3))) void*)l, 16, 0, 0);
}

// ---------------------------------------------------------------------------
// Fused prep (round-16, verbatim): xcast + W_attn^T + W_proj^T
// ---------------------------------------------------------------------------
__device__ __forceinline__ void wtrans_body(
    const float* __restrict__ W, short* __restrict__ Wt, int Ncols, int qcols,
    int bid2, int tid, short (*t)[33])
{
  const int nb = Ncols / 32;
  const int bn = bid2 % nb, bk = bid2 / nb;
  const int r = tid >> 3, c4 = (tid & 7) * 4;
  const float cs = (bn * 32 < qcols) ? SCALE2 : 1.f;
  f32x4 v = *reinterpret_cast<const f32x4*>(
      W + (size_t)(bk * 32 + r) * Ncols + bn * 32 + c4);
  #pragma unroll
  for (int j = 0; j < 4; ++j) t[r][c4 + j] = f2bs(v[j] * cs);
  __syncthreads();
  bs4 o;
  #pragma unroll
  for (int j = 0; j < 4; ++j) o[j] = t[c4 + j][r];
  *reinterpret_cast<bs4*>(Wt + (size_t)(bn * 32 + r) * KDIM + bk * 32 + c4) = o;
}

__global__ __launch_bounds__(256) void prep_kernel(
    const float* __restrict__ x,  short* __restrict__ xb,
    const float* __restrict__ Wa, short* __restrict__ WaT,
    const float* __restrict__ Wp, short* __restrict__ WpT)
{
  __shared__ short t[32][33];
  const int bid = blockIdx.x;
  const int tid = threadIdx.x;
  if (bid < 4096) {
    const int i = (bid * 256 + tid) * 8;
    f32x4 a = *reinterpret_cast<const f32x4*>(x + i);
    f32x4 b = *reinterpret_cast<const f32x4*>(x + i + 4);
    short8 o;
    #pragma unroll
    for (int j = 0; j < 4; ++j) { o[j] = f2bs(a[j]); o[4 + j] = f2bs(b[j]); }
    *reinterpret_cast<short8*>(xb + i) = o;
  } else if (bid < 7168) {
    wtrans_body(Wa, WaT, N_QKV, C_, bid - 4096, tid, t);
  } else {
    wtrans_body(Wp, WpT, C_, 0, bid - 7168, tid, t);
  }
}

// ---------------------------------------------------------------------------
// GEMM v3: BK=64 (round-15 structure) + bijective XCD swizzle (T1):
// swz = (bid%8)*(nwg/8) + bid/8 -> each XCD gets a contiguous block run,
// so the 24 (gemm1) / 8 (gemm2) blocks sharing an A-panel land on ONE
// XCD's L2 instead of being duplicated across all 8. nwg%8==0 for both
// launches (1536, 512) -> bijective (ERRATA #11 safe).
// ---------------------------------------------------------------------------
template<bool OUT_BF16>
__global__ __launch_bounds__(256) void gemm128b_kernel(
    const short* __restrict__ A, const short* __restrict__ Bt,
    const float* __restrict__ bias, void* __restrict__ outptr, int N, int nq,
    int nwg)
{
  __shared__ short As[128 * 64];
  __shared__ short Bs[128 * 64];

  const int tid  = threadIdx.x;
  const int lane = tid & 63;
  const int w    = tid >> 6;
  const int wr   = w >> 1, wc = w & 1;
  const int rl   = lane & 15, kg = lane >> 4;
  const int nblk = N >> 7;
  const int bid  = (int)blockIdx.x;
  const int swz  = (bid & 7) * (nwg >> 3) + (bid >> 3);   // XCD-contiguous
  const int m0 = (swz / nblk) << 7;
  const int n0 = (swz % nblk) << 7;

  f32x4 acc[4][4] = {};

  const int srow = w * 8 + (lane >> 3);
  const int scol = ((lane & 7) ^ ((lane >> 3) & 7)) * 8;
  const short* pa = A  + (size_t)(m0 + srow) * KDIM + scol;
  const short* pb = Bt + (size_t)(n0 + srow) * KDIM + scol;

  for (int k0 = 0; k0 < KDIM; k0 += 64) {
    __syncthreads();
    #pragma unroll
    for (int i = 0; i < 4; ++i) {
      gload16(pa + (size_t)i * 32 * KDIM + k0, &As[i * 2048 + w * 512]);
      gload16(pb + (size_t)i * 32 * KDIM + k0, &Bs[i * 2048 + w * 512]);
    }
    __syncthreads();

    #pragma unroll
    for (int kk = 0; kk < 2; ++kk) {
      const int sl = ((kk * 4 + kg) ^ (rl & 7)) * 8;
      short8 af[4], bf[4];
      #pragma unroll
      for (int i = 0; i < 4; ++i) {
        af[i] = *reinterpret_cast<short8*>(&As[(wr * 64 + i * 16 + rl) * 64 + sl]);
        bf[i] = *reinterpret_cast<short8*>(&Bs[(wc * 64 + i * 16 + rl) * 64 + sl]);
      }
      #pragma unroll
      for (int mi = 0; mi < 4; ++mi)
        #pragma unroll
        for (int ni = 0; ni < 4; ++ni)
          acc[mi][ni] = __builtin_amdgcn_mfma_f32_16x16x32_bf16(
              af[mi], bf[ni], acc[mi][ni], 0, 0, 0);
    }
  }

  #pragma unroll
  for (int ni = 0; ni < 4; ++ni) {
    const int col = n0 + wc * 64 + ni * 16 + rl;
    float bv = bias[col];
    if (col < nq) bv *= SCALE2;
    #pragma unroll
    for (int mi = 0; mi < 4; ++mi) {
      #pragma unroll
      for (int r = 0; r < 4; ++r) {
        const int row = m0 + wr * 64 + mi * 16 + kg * 4 + r;
        const float v = acc[mi][ni][r] + bv;
        if constexpr (OUT_BF16)
          ((short*)outptr)[(size_t)row * N + col] = f2bs(v);
        else
          ((float*)outptr)[(size_t)row * N + col] = v;
      }
    }
  }
}

// ---------------------------------------------------------------------------
// MFMA flash attention v13 (causal) — round-18 kernel VERBATIM (119.8us):
// 4-wave blocks, grid 1024, linear heavy-first qi, swapped QK^T 32x32x16,
// in-register softmax with tree reductions, packrn P^T, paired V staging.
// 8-wave pairing REVERTED (r19: 132us — light waves spin through heavy
// partner's barriers; 3rd structural attn regression -> attn is CLOSED).
// ---------------------------------------------------------------------------
__global__ __launch_bounds__(256) void attn_mfma13_kernel(
    const short* __restrict__ qkv, short* __restrict__ y)
{
  __shared__ short Ks[2][64 * 64];
  __shared__ short Vt[2][64 * 64];

  const int tid  = threadIdx.x;
  const int lane = tid & 63;
  const int w    = tid >> 6;
  const int q32  = lane & 31;
  const int hi   = lane >> 5;

  const int bid  = blockIdx.x;
  const int qi   = 15 - (bid >> 6);     // linear heavy-first
  const int bh   = bid & 63;
  const int b    = bh >> 4, h = bh & 15;
  const size_t bT = (size_t)b * T_;

  // ---- K staging (gload16, XOR-swizzled source) ----
  const int kr0 = tid >> 3;
  const int kl0 = (tid & 7) ^ ((tid >> 3) & 7);
  const int kr1 = (tid + 256) >> 3;
  const int kl1 = (tid & 7) ^ (((tid + 256) >> 3) & 7);
  const size_t kbase0 = (bT + kr0) * N_QKV + C_ + h * HD + kl0 * 8;
  const size_t kbase1 = (bT + kr1) * N_QKV + C_ + h * HD + kl1 * 8;
  short* const kdst0 = &Ks[0][(w * 64) * 8];
  short* const kdst1 = &Ks[0][(w * 64 + 256) * 8];

  // ---- V staging (paired): keys (2kp, 2kp+1), d octet [d0, d0+8) ----
  const int kp = tid & 31;
  const int d0 = (tid >> 5) * 8;
  const size_t vbaseA = (bT + 2 * kp) * N_QKV + 2 * C_ + h * HD + d0;
  const size_t vbaseB = vbaseA + N_QKV;
  const int vws = ((kp >> 2) << 3) + ((kp & 3) << 1);  // short offset pre-XOR

  const int ksl = q32 & 7;              // frag-read swizzle phase

  const int nkb = 2 * qi + 2;
  const int wq0 = qi * 128 + w * 32;
  const int q   = wq0 + q32;            // this lane's q-row

  // Q B-frags: col=q, k = d = kd*16 + hi*8 + j  (pre-scaled by SCALE2)
  short8 qf[4];
  #pragma unroll
  for (int kd = 0; kd < 4; ++kd)
    qf[kd] = *reinterpret_cast<const short8*>(
        qkv + (bT + q) * N_QKV + h * HD + kd * 16 + hi * 8);

  f32x16 o0 = {}, o1 = {};              // O^T, d-tiles 0/1
  float m_ = -INFINITY, l_ = 0.f;

  // prologue: stage tile 0 into buffer 0
  {
    gload16(qkv + kbase0, kdst0);
    gload16(qkv + kbase1, kdst1);
    short8 va = *reinterpret_cast<const short8*>(qkv + vbaseA);
    short8 vb = *reinterpret_cast<const short8*>(qkv + vbaseB);
    #pragma unroll
    for (int j = 0; j < 8; ++j) {
      unsigned pw = (unsigned)(unsigned short)va[j] |
                    ((unsigned)(unsigned short)vb[j] << 16);
      *reinterpret_cast<unsigned*>(
          &Vt[0][(d0 + j) * 64 + (vws ^ (j << 3))]) = pw;
    }
  }
  __syncthreads();

  int cur = 0;
  for (int kb = 0; kb < nkb; ++kb) {
    const bool more = (kb + 1 < nkb);
    short8 va, vb;
    if (more) {
      const size_t koff = (size_t)(kb + 1) * 64 * N_QKV;
      gload16(qkv + kbase0 + koff, kdst0 + (cur ^ 1) * 4096);
      gload16(qkv + kbase1 + koff, kdst1 + (cur ^ 1) * 4096);
      va = *reinterpret_cast<const short8*>(qkv + vbaseA + koff);
      vb = *reinterpret_cast<const short8*>(qkv + vbaseB + koff);
    }

    const int kmin = kb * 64;
    if (kmin <= wq0 + 31) {
      const short* ksc = &Ks[cur][0];
      const short* vtc = &Vt[cur][0];

      // ---- QK^T (swapped): keys = kmin + c*32 + (e&3)+8*(e>>2)+4*hi ----
      f32x16 s0 = {}, s1 = {};
      #pragma unroll
      for (int kd = 0; kd < 4; ++kd) {
        const int sl = ((2 * kd + hi) ^ ksl) * 8;
        short8 kf0 = *reinterpret_cast<const short8*>(&ksc[q32 * 64 + sl]);
        short8 kf1 = *reinterpret_cast<const short8*>(&ksc[(32 + q32) * 64 + sl]);
        s0 = __builtin_amdgcn_mfma_f32_32x32x16_bf16(kf0, qf[kd], s0, 0, 0, 0);
        s1 = __builtin_amdgcn_mfma_f32_32x32x16_bf16(kf1, qf[kd], s1, 0, 0, 0);
      }

      // ---- causal mask (exp2-domain scores via Q pre-scale) ----
      if (kmin + 63 > wq0) {
        const int qrel = q - kmin - 4 * hi;
        #pragma unroll
        for (int e = 0; e < 16; ++e) {
          const int ko = (e & 3) + 8 * (e >> 2);
          if (ko > qrel)      s0[e] = -INFINITY;
          if (ko + 32 > qrel) s1[e] = -INFINITY;
        }
      }

      // ---- row max: pairwise tree (depth ~5) ----
      float mv[16];
      #pragma unroll
      for (int e = 0; e < 16; ++e) mv[e] = fmaxf(s0[e], s1[e]);
      #pragma unroll
      for (int st = 8; st >= 1; st >>= 1)
        #pragma unroll
        for (int e = 0; e < st; ++e) mv[e] = fmaxf(mv[e], mv[e + st]);
      float mx = fmaxf(mv[0], __shfl_xor(mv[0], 32, 64));

      // ---- defer-max: rescale only when max grew by > 8 (exp2 domain) ----
      if (!__all(mx <= m_ + 8.f)) {
        const float mn = fmaxf(m_, mx);
        const float cr = exp2f(m_ - mn);
        m_ = mn;
        l_ *= cr;
        #pragma unroll
        for (int e = 0; e < 16; ++e) { o0[e] *= cr; o1[e] *= cr; }
      }

      // ---- exp + sum tree ----
      #pragma unroll
      for (int e = 0; e < 16; ++e) {
        s0[e] = exp2f(s0[e] - m_);
        s1[e] = exp2f(s1[e] - m_);
      }
      float sv[16];
      #pragma unroll
      for (int e = 0; e < 16; ++e) sv[e] = s0[e] + s1[e];
      #pragma unroll
      for (int st = 8; st >= 1; st >>= 1)
        #pragma unroll
        for (int e = 0; e < st; ++e) sv[e] += sv[e + st];
      l_ += sv[0] + __shfl_xor(sv[0], 32, 64);

      // ---- P^T B-frags: packrn + shfl_xor + hi-select ----
      unsigned pk[2][4][2], sw[2][4][2];
      #pragma unroll
      for (int gg = 0; gg < 4; ++gg)
        #pragma unroll
        for (int p = 0; p < 2; ++p) {
          pk[0][gg][p] = packrn(s0[4 * gg + 2 * p], s0[4 * gg + 2 * p + 1]);
          pk[1][gg][p] = packrn(s1[4 * gg + 2 * p], s1[4 * gg + 2 * p + 1]);
          sw[0][gg][p] = (unsigned)__shfl_xor((int)pk[0][gg][p], 32, 64);
          sw[1][gg][p] = (unsigned)__shfl_xor((int)pk[1][gg][p], 32, 64);
        }

      #pragma unroll
      for (int kk = 0; kk < 4; ++kk) {
        const int c = kk >> 1, a2 = 2 * (kk & 1);
        u32x4 t;
        t[0] = hi ? sw[c][a2 + 1][0] : pk[c][a2][0];
        t[1] = hi ? sw[c][a2 + 1][1] : pk[c][a2][1];
        t[2] = hi ? pk[c][a2 + 1][0] : sw[c][a2][0];
        t[3] = hi ? pk[c][a2 + 1][1] : sw[c][a2][1];
        const short8 pb = __builtin_bit_cast(short8, t);
        const int sl = ((2 * kk + hi) ^ ksl) * 8;
        short8 vf0 = *reinterpret_cast<const short8*>(&vtc[q32 * 64 + sl]);
        short8 vf1 = *reinterpret_cast<const short8*>(&vtc[(32 + q32) * 64 + sl]);
        o0 = __builtin_amdgcn_mfma_f32_32x32x16_bf16(vf0, pb, o0, 0, 0, 0);
        o1 = __builtin_amdgcn_mfma_f32_32x32x16_bf16(vf1, pb, o1, 0, 0, 0);
      }
    }

    if (more) {
      #pragma unroll
      for (int j = 0; j < 8; ++j) {
        unsigned pw = (unsigned)(unsigned short)va[j] |
                      ((unsigned)(unsigned short)vb[j] << 16);
        *reinterpret_cast<unsigned*>(
            &Vt[cur ^ 1][(d0 + j) * 64 + (vws ^ (j << 3))]) = pw;
      }
    }
    __syncthreads();
    cur ^= 1;
  }

  // ---- epilogue: O^T row d = dt*32 + 8g + 4hi + t, col q; bs4 stores ----
  const float inv = 1.f / l_;
  short* const yp = y + (bT + q) * C_ + h * HD;
  #pragma unroll
  for (int gg = 0; gg < 4; ++gg) {
    bs4 ov0, ov1;
    #pragma unroll
    for (int t = 0; t < 4; ++t) {
      ov0[t] = f2bs(o0[4 * gg + t] * inv);
      ov1[t] = f2bs(o1[4 * gg + t] * inv);
    }
    *reinterpret_cast<bs4*>(yp + 8 * gg + 4 * hi)      = ov0;
    *reinterpret_cast<bs4*>(yp + 32 + 8 * gg + 4 * hi) = ov1;
  }
}

extern "C" void kernel_launch(void* const* d_in, const int* in_sizes, int n_in,
                              void* d_out, int out_size, void* d_ws, size_t ws_size,
                              hipStream_t stream) {
  const float* x  = (const float*)d_in[0];
  const float* Wa = (const float*)d_in[1];
  const float* ba = (const float*)d_in[2];
  const float* Wp = (const float*)d_in[3];
  const float* bp = (const float*)d_in[4];

  short* qkvb = (short*)d_ws;                       // [8192,3072] bf16 (50.3MB)
  short* xb   = qkvb + (size_t)M_ * N_QKV;          // [8192,1024] bf16 (16.8MB)
  short* yb   = xb;                                 // overlaid: xb dead after gemm1
  short* WaT  = xb + (size_t)M_ * C_;               // [3072,1024] bf16 (6.3MB)
  short* WpT  = WaT + (size_t)N_QKV * KDIM;         // [1024,1024] bf16 (2.1MB)

  prep_kernel<<<8192, 256, 0, stream>>>(x, xb, Wa, WaT, Wp, WpT);
  gemm128b_kernel<true><<<(M_ / 128) * (N_QKV / 128), 256, 0, stream>>>(
      xb, WaT, ba, qkvb, N_QKV, C_, (M_ / 128) * (N_QKV / 128));
  attn_mfma13_kernel<<<16 * B_ * NH, 256, 0, stream>>>(qkvb, yb);
  gemm128b_kernel<false><<<(M_ / 128) * (C_ / 128), 256, 0, stream>>>(
      yb, WpT, bp, d_out, C_, 0, (M_ / 128) * (C_ / 128));
}